// Round 8
// baseline (1515.287 us; speedup 1.0000x reference)
//
#include <hip/hip_runtime.h>
#include <cstring>
#include <cstdio>

typedef __attribute__((ext_vector_type(8))) short short8;
typedef __attribute__((ext_vector_type(4))) float f32x4;
typedef __attribute__((ext_vector_type(4))) unsigned u32x4;

__device__ __forceinline__ short f2bf(float f){
  unsigned u; __builtin_memcpy(&u, &f, 4);
  u += 0x7FFFu + ((u >> 16) & 1u);
  return (short)(u >> 16);
}
__device__ __forceinline__ float bf2f(short s){
  unsigned u = ((unsigned)(unsigned short)s) << 16;
  float f; __builtin_memcpy(&f, &u, 4);
  return f;
}
__device__ __forceinline__ void split2(float v, short& hi, short& lo){
  hi = f2bf(v);
  float r = v - bf2f(hi);   // exact (Sterbenz)
  lo = f2bf(r);
}
__device__ __forceinline__ unsigned pack2(float v){
  short hi, lo; split2(v, hi, lo);
  return (((unsigned)(unsigned short)hi) << 16) | (unsigned)(unsigned short)lo;
}
__device__ __forceinline__ float tanh_fast(float x){
  float e = __expf(2.0f * x);
  return 1.0f - 2.0f / (e + 1.0f);
}

// swizzled LDS short-index for h planes: element (r,k) -> idx, XOR bits 3..5
#define HIDX(r,k) ((((r) * 512) + (k)) ^ (((r) & 7) << 3))

// ---------------------------------------------------------------------------
// K0a: transpose + hi/lo split
// ---------------------------------------------------------------------------
__global__ void transpose_split(const float* __restrict__ in,
                                short* __restrict__ outh, short* __restrict__ outl,
                                int R, int C){
  int idx = blockIdx.x * 256 + threadIdx.x;
  if (idx < R * C){
    int r = idx / C, c = idx % C;
    short h, l; split2(in[(size_t)r * C + c], h, l);
    outh[(size_t)c * R + r] = h;
    outl[(size_t)c * R + r] = l;
  }
}

// K0b: plain transpose to single bf16 (for Wout)
__global__ void transpose_to_bf16(const float* __restrict__ in, short* __restrict__ out,
                                  int R, int C){
  int idx = blockIdx.x * 256 + threadIdx.x;
  if (idx < R * C){
    int r = idx / C, c = idx % C;
    out[(size_t)c * R + r] = f2bf(in[(size_t)r * C + c]);
  }
}

// ---------------------------------------------------------------------------
// K1: x [B=256][D=256][T=256] f32 -> xT_hi/xT_lo [(t*256+b)][d] bf16
// ---------------------------------------------------------------------------
__global__ __launch_bounds__(256) void transpose_x_split(const float* __restrict__ x,
                                                         short* __restrict__ xTh,
                                                         short* __restrict__ xTl){
  __shared__ float tile[64][65];
  const int b = blockIdx.x, d0 = blockIdx.y * 64, t0 = blockIdx.z * 64;
  const int tid = threadIdx.x;
  const float* xp = x + ((size_t)b * 256 + d0) * 256 + t0;
  for (int v = tid; v < 1024; v += 256){
    int r = v >> 4, c4 = (v & 15) * 4;
    float4 f = *(const float4*)(xp + (size_t)r * 256 + c4);
    tile[r][c4+0] = f.x; tile[r][c4+1] = f.y; tile[r][c4+2] = f.z; tile[r][c4+3] = f.w;
  }
  __syncthreads();
  for (int v = tid; v < 512; v += 256){
    int j = v >> 3, i8 = (v & 7) * 8;
    short8 oh, ol;
    #pragma unroll
    for (int u = 0; u < 8; ++u){ short h, l; split2(tile[i8 + u][j], h, l); oh[u] = h; ol[u] = l; }
    size_t off = ((size_t)(t0 + j) * 256 + b) * 256 + d0 + i8;
    *(short8*)(xTh + off) = oh;
    *(short8*)(xTl + off) = ol;
  }
}

// ---------------------------------------------------------------------------
// K2: split-precision GEMM (3-product), 128x128 tile, 4 waves (2x2 of 64x64).
// ---------------------------------------------------------------------------
__global__ __launch_bounds__(256) void gemm1_split(
    const short* __restrict__ Ah, const short* __restrict__ Al,
    const short* __restrict__ Bh, const short* __restrict__ Bl,
    const float* __restrict__ bias, float* __restrict__ C0, float* __restrict__ C1,
    int M, int N, int K)
{
  __shared__ short lAh[128][72];
  __shared__ short lAl[128][72];
  __shared__ short lBh[128][72];
  __shared__ short lBl[128][72];
  const int m0 = blockIdx.y * 128, n0 = blockIdx.x * 128;
  const int tid = threadIdx.x;
  const int lane = tid & 63, wave = tid >> 6;
  const int wm = (wave >> 1) * 64, wn = (wave & 1) * 64;
  f32x4 acc[4][4] = {};
  for (int k0 = 0; k0 < K; k0 += 64){
    __syncthreads();
    for (int v = tid; v < 4096; v += 256){
      int sel = v >> 10, idx = v & 1023;
      int r = idx >> 3, c = (idx & 7) * 8;
      const short* src = (sel == 0) ? Ah + (size_t)(m0 + r) * K + k0 + c
                       : (sel == 1) ? Al + (size_t)(m0 + r) * K + k0 + c
                       : (sel == 2) ? Bh + (size_t)(n0 + r) * K + k0 + c
                                    : Bl + (size_t)(n0 + r) * K + k0 + c;
      short8 val = *(const short8*)src;
      short* dst = (sel == 0) ? &lAh[r][c] : (sel == 1) ? &lAl[r][c]
                 : (sel == 2) ? &lBh[r][c] : &lBl[r][c];
      *(short8*)dst = val;
    }
    __syncthreads();
    #pragma unroll
    for (int kk = 0; kk < 64; kk += 32){
      int ko = kk + (lane >> 4) * 8;
      short8 ah[4], al[4], bh[4], bl[4];
      #pragma unroll
      for (int i = 0; i < 4; ++i){
        ah[i] = *(const short8*)&lAh[wm + i * 16 + (lane & 15)][ko];
        al[i] = *(const short8*)&lAl[wm + i * 16 + (lane & 15)][ko];
        bh[i] = *(const short8*)&lBh[wn + i * 16 + (lane & 15)][ko];
        bl[i] = *(const short8*)&lBl[wn + i * 16 + (lane & 15)][ko];
      }
      #pragma unroll
      for (int i = 0; i < 4; ++i)
      #pragma unroll
      for (int j = 0; j < 4; ++j){
        acc[i][j] = __builtin_amdgcn_mfma_f32_16x16x32_bf16(ah[i], bh[j], acc[i][j], 0, 0, 0);
        acc[i][j] = __builtin_amdgcn_mfma_f32_16x16x32_bf16(ah[i], bl[j], acc[i][j], 0, 0, 0);
        acc[i][j] = __builtin_amdgcn_mfma_f32_16x16x32_bf16(al[i], bh[j], acc[i][j], 0, 0, 0);
      }
    }
  }
  const int cr = (lane >> 4) * 4, cc = lane & 15;
  #pragma unroll
  for (int i = 0; i < 4; ++i)
  #pragma unroll
  for (int j = 0; j < 4; ++j){
    int row = m0 + wm + i * 16 + cr;
    int col = n0 + wn + j * 16 + cc;
    float bv = bias[col];
    float* base = (row < 32768) ? C0 : C1;
    int rr = (row < 32768) ? row : row - 32768;
    #pragma unroll
    for (int r = 0; r < 4; ++r){
      base[(size_t)(rr + r) * N + col] = acc[i][j][r] + bv;
    }
  }
}

// ---------------------------------------------------------------------------
// K3 v8: team-parallel recurrence with 2-group software pipeline.
// 128 blocks = 16 teams (16 batch rows) x 8 N-slices. Each block alternates
// group A (team rows 0-7) and B (rows 8-15); while one group's h propagates
// through L3, the other's unpack+MFMA runs -> sync latency hidden.
// Per-group protocol = proven v5/v7 agent-scope flag-gated exchange, with
// s_sleep backoff restored and states stores inside the publish drain.
// ---------------------------------------------------------------------------
__global__ __launch_bounds__(256, 1) void rnn_steps_v8(
    const float* __restrict__ xp0,    // t<128:  [(t*256+b)][512] f32
    const float* __restrict__ xp1,    // t>=128: [((t-128)*256+b)][512] f32
    const short* __restrict__ WhTh,   // [512][512] bf16 hi, [n][k]
    const short* __restrict__ WhTl,   // [512][512] bf16 lo
    const float* __restrict__ init,   // [512]
    short* __restrict__ states,       // [(b*256+t)][512] bf16
    unsigned* __restrict__ pay,       // [2][16][16][512] u32 payload
    unsigned* __restrict__ flags)     // [2][2][16][32] u32 wave-flags
{
  __shared__ short hhA[16 * 512];
  __shared__ short hlA[16 * 512];
  __shared__ short hhB[16 * 512];
  __shared__ short hlB[16 * 512];
  const int tid = threadIdx.x, lane = tid & 63, wave = tid >> 6;
  const int team = blockIdx.x & 15, slice = blockIdx.x >> 4;
  const int nc = slice * 64 + wave * 16;          // this wave's global col base

  // ---- prologue: Wh B-fragments into registers (hi+lo, 16 k-steps) ----
  short8 Bh[16], Bl[16];
  {
    const size_t col = (size_t)(nc + (lane & 15));
    const int kb0 = (lane >> 4) * 8;
    #pragma unroll
    for (int ks = 0; ks < 16; ++ks){
      Bh[ks] = *(const short8*)(WhTh + col * 512 + ks * 32 + kb0);
      Bl[ks] = *(const short8*)(WhTl + col * 512 + ks * 32 + kb0);
    }
    #pragma unroll
    for (int ks = 0; ks < 16; ++ks){
      asm volatile("" : "+v"(Bh[ks]), "+v"(Bl[ks]));
    }
  }
  // zero pad rows 8..15; fill rows 0..7 with init (both plane pairs)
  for (int v = tid; v < 8 * 512; v += 256){
    int r = 8 + (v >> 9), k = v & 511;
    hhA[HIDX(r, k)] = 0; hlA[HIDX(r, k)] = 0;
    hhB[HIDX(r, k)] = 0; hlB[HIDX(r, k)] = 0;
  }
  for (int v = tid; v < 8 * 512; v += 256){
    int r = v >> 9, k = v & 511;
    short hi, lo; split2(init[k], hi, lo);
    hhA[HIDX(r, k)] = hi; hlA[HIDX(r, k)] = lo;
    hhB[HIDX(r, k)] = hi; hlB[HIDX(r, k)] = lo;
  }
  __syncthreads();

  // ---- per-lane constants (same verified mapping as r2..r7) ----
  const int cc = lane & 15;
  const bool islo = (lane < 32);
  const int mbase = ((lane & 31) >> 4) * 4;
  const int m_0 = mbase + (islo ? 0 : 2);
  const int m_1 = mbase + (islo ? 1 : 3);
  const int n = nc + cc;                           // global col of this lane
  float hrA0 = init[n], hrA1 = init[n];
  float hrB0 = init[n], hrB1 = init[n];

  const int am = lane & 15, kb = (lane >> 4) * 8;
  const int rr = tid & 7, c0 = ((tid >> 3) & 31) * 16;

  for (int t = 0; t < 256; ++t){
    #pragma unroll
    for (int g = 0; g < 2; ++g){
      short* hh = (g == 0) ? hhA : hhB;
      short* hl = (g == 0) ? hlA : hlB;
      float& hr0 = (g == 0) ? hrA0 : hrB0;
      float& hr1 = (g == 0) ? hrA1 : hrB1;
      const int b0g = team * 16 + g * 8;           // batch-row base of group

      float xv0, xv1;
      if (t == 0){
        xv0 = xp0[(size_t)(b0g + m_0) * 512 + n];
        xv1 = xp0[(size_t)(b0g + m_1) * 512 + n];
      } else {
        const unsigned tagv = (unsigned)t;
        // 1) poll group's 32 wave-flags (one 128B line), s_sleep backoff
        const unsigned* flg = flags + ((((size_t)(t & 1)) * 2 + g) * 16 + team) * 32
                              + (lane & 7) * 4;
        while (true){
          u32x4 f;
          asm volatile("global_load_dwordx4 %0, %1, off sc0 sc1" : "=&v"(f) : "v"(flg) : "memory");
          asm volatile("s_waitcnt vmcnt(0)" : "+v"(f) :: "memory");
          bool ok = (f.x >= tagv) && (f.y >= tagv) && (f.z >= tagv) && (f.w >= tagv);
          if (__all(ok)) break;
          __builtin_amdgcn_s_sleep(1);
        }
        // 2) issue payload (4x dwordx4) then xproj (2x dword); wait payload only
        const unsigned* src = pay + ((((size_t)(t & 1)) * 16 + team) * 16 + g * 8 + rr) * 512 + c0;
        u32x4 g0, g1, g2, g3;
        asm volatile("global_load_dwordx4 %0, %1, off sc0 sc1" : "=&v"(g0) : "v"(src +  0) : "memory");
        asm volatile("global_load_dwordx4 %0, %1, off sc0 sc1" : "=&v"(g1) : "v"(src +  4) : "memory");
        asm volatile("global_load_dwordx4 %0, %1, off sc0 sc1" : "=&v"(g2) : "v"(src +  8) : "memory");
        asm volatile("global_load_dwordx4 %0, %1, off sc0 sc1" : "=&v"(g3) : "v"(src + 12) : "memory");
        const float* xpb = (t < 128) ? xp0 : xp1;
        const int tt = (t < 128) ? t : t - 128;
        const float* xa0 = xpb + ((size_t)tt * 256 + b0g + m_0) * 512 + n;
        const float* xa1 = xpb + ((size_t)tt * 256 + b0g + m_1) * 512 + n;
        asm volatile("global_load_dword %0, %1, off" : "=&v"(xv0) : "v"(xa0) : "memory");
        asm volatile("global_load_dword %0, %1, off" : "=&v"(xv1) : "v"(xa1) : "memory");
        // barrier: all waves past their reads of this group's LDS planes
        __syncthreads();
        // in-order vmcnt: waits the 4 payload loads, leaves the 2 xproj in flight
        asm volatile("s_waitcnt vmcnt(2)"
                     : "+v"(g0), "+v"(g1), "+v"(g2), "+v"(g3) :: "memory");
        short8 h0v, h1v, l0v, l1v;
        h0v[0] = (short)(g0.x >> 16); h0v[1] = (short)(g0.y >> 16);
        h0v[2] = (short)(g0.z >> 16); h0v[3] = (short)(g0.w >> 16);
        h0v[4] = (short)(g1.x >> 16); h0v[5] = (short)(g1.y >> 16);
        h0v[6] = (short)(g1.z >> 16); h0v[7] = (short)(g1.w >> 16);
        h1v[0] = (short)(g2.x >> 16); h1v[1] = (short)(g2.y >> 16);
        h1v[2] = (short)(g2.z >> 16); h1v[3] = (short)(g2.w >> 16);
        h1v[4] = (short)(g3.x >> 16); h1v[5] = (short)(g3.y >> 16);
        h1v[6] = (short)(g3.z >> 16); h1v[7] = (short)(g3.w >> 16);
        l0v[0] = (short)(g0.x & 0xffffu); l0v[1] = (short)(g0.y & 0xffffu);
        l0v[2] = (short)(g0.z & 0xffffu); l0v[3] = (short)(g0.w & 0xffffu);
        l0v[4] = (short)(g1.x & 0xffffu); l0v[5] = (short)(g1.y & 0xffffu);
        l0v[6] = (short)(g1.z & 0xffffu); l0v[7] = (short)(g1.w & 0xffffu);
        l1v[0] = (short)(g2.x & 0xffffu); l1v[1] = (short)(g2.y & 0xffffu);
        l1v[2] = (short)(g2.z & 0xffffu); l1v[3] = (short)(g2.w & 0xffffu);
        l1v[4] = (short)(g3.x & 0xffffu); l1v[5] = (short)(g3.y & 0xffffu);
        l1v[6] = (short)(g3.z & 0xffffu); l1v[7] = (short)(g3.w & 0xffffu);
        *(short8*)&hh[HIDX(rr, c0)]     = h0v;
        *(short8*)&hh[HIDX(rr, c0 + 8)] = h1v;
        *(short8*)&hl[HIDX(rr, c0)]     = l0v;
        *(short8*)&hl[HIDX(rr, c0 + 8)] = l1v;
        __syncthreads();   // group's h_t complete in LDS
      }

      // MFMA: 3 independent accumulator chains (hh, hl, lh)
      f32x4 ahh = {}, ahl = {}, alh = {};
      #pragma unroll
      for (int ks = 0; ks < 16; ++ks){
        short8 Ah = *(const short8*)&hh[HIDX(am, ks * 32 + kb)];
        short8 Al = *(const short8*)&hl[HIDX(am, ks * 32 + kb)];
        ahh = __builtin_amdgcn_mfma_f32_16x16x32_bf16(Ah, Bh[ks], ahh, 0, 0, 0);
        ahl = __builtin_amdgcn_mfma_f32_16x16x32_bf16(Ah, Bl[ks], ahl, 0, 0, 0);
        alh = __builtin_amdgcn_mfma_f32_16x16x32_bf16(Al, Bh[ks], alh, 0, 0, 0);
      }
      const float s0 = ahh[0] + (ahl[0] + alh[0]);
      const float s1 = ahh[1] + (ahl[1] + alh[1]);
      const float s2 = ahh[2] + (ahl[2] + alh[2]);
      const float s3 = ahh[3] + (ahl[3] + alh[3]);
      const float t2 = __shfl(s2, lane ^ 32);
      const float t3 = __shfl(s3, lane ^ 32);
      const float v0 = islo ? s0 : t2;
      const float v1 = islo ? s1 : t3;

      if (t > 0){
        asm volatile("s_waitcnt vmcnt(0)" : "+v"(xv0), "+v"(xv1) :: "memory");
      }
      const float hn0 = tanh_fast(xv0 + v0) + hr0;
      const float hn1 = tanh_fast(xv1 + v1) + hr1;
      hr0 = hn0; hr1 = hn1;

      if (t < 255){
        // publish payload for step t+1 (parity (t+1)&1), then states, then
        // one drain covering both, then per-wave flag.
        unsigned* dst = pay + ((((size_t)((t + 1) & 1)) * 16 + team) * 16 + g * 8) * 512;
        unsigned w0 = pack2(hn0), w1 = pack2(hn1);
        unsigned* a0 = dst + (size_t)m_0 * 512 + n;
        unsigned* a1 = dst + (size_t)m_1 * 512 + n;
        asm volatile("global_store_dword %0, %1, off sc0 sc1" :: "v"(a0), "v"(w0) : "memory");
        asm volatile("global_store_dword %0, %1, off sc0 sc1" :: "v"(a1), "v"(w1) : "memory");
        states[((size_t)(b0g + m_0) * 256 + t) * 512 + n] = f2bf(hn0);
        states[((size_t)(b0g + m_1) * 256 + t) * 512 + n] = f2bf(hn1);
        asm volatile("s_waitcnt vmcnt(0)" ::: "memory");
        if (lane == 0){
          unsigned* fdst = flags + ((((size_t)((t + 1) & 1)) * 2 + g) * 16 + team) * 32
                           + slice * 4 + wave;
          unsigned tagn = (unsigned)(t + 1);
          asm volatile("global_store_dword %0, %1, off sc0 sc1" :: "v"(fdst), "v"(tagn) : "memory");
        }
      } else {
        states[((size_t)(b0g + m_0) * 256 + t) * 512 + n] = f2bf(hn0);
        states[((size_t)(b0g + m_1) * 256 + t) * 512 + n] = f2bf(hn1);
      }
    }
  }
}

// ---------------------------------------------------------------------------
// K4: single-product bf16 GEMM, 128x128 tile, 4 waves (2x2 of 64x64), fp32 out.
// ---------------------------------------------------------------------------
__global__ __launch_bounds__(256) void gemm_bias_f32(
    const short* __restrict__ A, const short* __restrict__ Bt,
    const float* __restrict__ bias, float* __restrict__ C,
    int M, int N, int K)
{
  __shared__ short lA[128][72];
  __shared__ short lB[128][72];
  const int m0 = blockIdx.y * 128, n0 = blockIdx.x * 128;
  const int tid = threadIdx.x;
  const int lane = tid & 63, wave = tid >> 6;
  const int wm = (wave >> 1) * 64, wn = (wave & 1) * 64;
  f32x4 acc[4][4] = {};
  for (int k0 = 0; k0 < K; k0 += 64){
    __syncthreads();
    for (int v = tid; v < 2048; v += 256){
      int sel = v >> 10, idx = v & 1023;
      int r = idx >> 3, c = (idx & 7) * 8;
      const short* src = (sel == 0) ? A + (size_t)(m0 + r) * K + k0 + c
                                    : Bt + (size_t)(n0 + r) * K + k0 + c;
      short8 val = *(const short8*)src;
      short* dst = (sel == 0) ? &lA[r][c] : &lB[r][c];
      *(short8*)dst = val;
    }
    __syncthreads();
    #pragma unroll
    for (int kk = 0; kk < 64; kk += 32){
      int ko = kk + (lane >> 4) * 8;
      short8 a[4], b[4];
      #pragma unroll
      for (int i = 0; i < 4; ++i){
        a[i] = *(const short8*)&lA[wm + i * 16 + (lane & 15)][ko];
        b[i] = *(const short8*)&lB[wn + i * 16 + (lane & 15)][ko];
      }
      #pragma unroll
      for (int i = 0; i < 4; ++i)
      #pragma unroll
      for (int j = 0; j < 4; ++j){
        acc[i][j] = __builtin_amdgcn_mfma_f32_16x16x32_bf16(a[i], b[j], acc[i][j], 0, 0, 0);
      }
    }
  }
  const int cr = (lane >> 4) * 4, cc = lane & 15;
  #pragma unroll
  for (int i = 0; i < 4; ++i)
  #pragma unroll
  for (int j = 0; j < 4; ++j){
    int row = m0 + wm + i * 16 + cr;
    int col = n0 + wn + j * 16 + cc;
    float bv = bias[col];
    #pragma unroll
    for (int r = 0; r < 4; ++r){
      C[(size_t)(row + r) * N + col] = acc[i][j][r] + bv;
    }
  }
}

// ---------------------------------------------------------------------------
extern "C" void kernel_launch(void* const* d_in, const int* in_sizes, int n_in,
                              void* d_out, int out_size, void* d_ws, size_t ws_size,
                              hipStream_t stream){
  (void)in_sizes; (void)n_in; (void)out_size;
  const float* x    = (const float*)d_in[0];
  const float* Wx   = (const float*)d_in[1];
  const float* Wh   = (const float*)d_in[2];
  const float* bias = (const float*)d_in[3];
  const float* Wout = (const float*)d_in[4];
  const float* bout = (const float*)d_in[5];
  const float* init = (const float*)d_in[6];
  float* out = (float*)d_out;

  char* p = (char*)d_ws;
  // [0,64Mi): xT hi+lo during GEMM1, then states (written only by rnn).
  short* xTh    = (short*)(p);
  short* xTl    = (short*)(p + 33554432);
  short* states = (short*)(p);
  // xproj fp32: rows [0,32768) in ws, rows [32768,65536) in d_out (dead until GEMM2).
  float* xproj0 = (float*)(p + 67108864);     // 64 MiB
  float* xproj1 = (float*)d_out;              // 64 MiB
  short* WxTh   = (short*)(p + 134217728);    // 256 KiB
  short* WxTl   = (short*)(p + 134479872);    // 256 KiB
  short* WhTh   = (short*)(p + 134742016);    // 512 KiB
  short* WhTl   = (short*)(p + 135266304);    // 512 KiB
  short* WoutT  = (short*)(p + 135790592);    // 256 KiB
  unsigned* pay   = (unsigned*)(p + 136052736); // 1 MiB  [2][16][16][512] u32
  unsigned* flags = (unsigned*)(p + 137101312); // 8 KiB  [2][2][16][32] u32
  if (ws_size < 137109504u){
    fprintf(stderr, "kernel_launch: ws_size=%zu < 137109504 needed\n", ws_size);
  }

  // clear flags every launch (graph-capture-safe); payload gated by flags
  hipMemsetAsync(flags, 0, 8192, stream);

  transpose_split<<<(256*512 + 255)/256, 256, 0, stream>>>(Wx, WxTh, WxTl, 256, 512);
  transpose_split<<<(512*512 + 255)/256, 256, 0, stream>>>(Wh, WhTh, WhTl, 512, 512);
  transpose_to_bf16<<<(512*256 + 255)/256, 256, 0, stream>>>(Wout, WoutT, 512, 256);
  transpose_x_split<<<dim3(256, 4, 4), 256, 0, stream>>>(x, xTh, xTl);
  // xproj = xT @ Wx + b at ~fp32 precision (3-product split MFMA), 128^2 tile
  gemm1_split<<<dim3(4, 512), 256, 0, stream>>>(xTh, xTl, WxTh, WxTl, bias,
                                                xproj0, xproj1, 65536, 512, 256);
  // recurrence: 16 teams x 8 slices, 2-group pipelined exchange
  rnn_steps_v8<<<128, 256, 0, stream>>>(xproj0, xproj1, WhTh, WhTl, init,
                                        states, pay, flags);
  // out = states @ Wout + bout (single bf16 product), 128^2 tile
  gemm_bias_f32<<<dim3(2, 512), 256, 0, stream>>>(states, WoutT, bout, out, 65536, 256, 512);
}

// Round 9
// 977.892 us; speedup vs baseline: 1.5495x; 1.5495x over previous
//
#include <hip/hip_runtime.h>
#include <cstring>
#include <cstdio>

typedef __attribute__((ext_vector_type(8))) short short8;
typedef __attribute__((ext_vector_type(4))) float f32x4;
typedef __attribute__((ext_vector_type(4))) unsigned u32x4;

__device__ __forceinline__ short f2bf(float f){
  unsigned u; __builtin_memcpy(&u, &f, 4);
  u += 0x7FFFu + ((u >> 16) & 1u);
  return (short)(u >> 16);
}
__device__ __forceinline__ float bf2f(short s){
  unsigned u = ((unsigned)(unsigned short)s) << 16;
  float f; __builtin_memcpy(&f, &u, 4);
  return f;
}
__device__ __forceinline__ void split2(float v, short& hi, short& lo){
  hi = f2bf(v);
  float r = v - bf2f(hi);   // exact (Sterbenz)
  lo = f2bf(r);
}
__device__ __forceinline__ unsigned pack2(float v){
  short hi, lo; split2(v, hi, lo);
  return (((unsigned)(unsigned short)hi) << 16) | (unsigned)(unsigned short)lo;
}
__device__ __forceinline__ float tanh_fast(float x){
  float e = __expf(2.0f * x);
  return 1.0f - 2.0f / (e + 1.0f);
}

// swizzled LDS short-index for h planes: element (r,k) -> idx, XOR bits 3..5
#define HIDX(r,k) ((((r) * 512) + (k)) ^ (((r) & 7) << 3))

// ---------------------------------------------------------------------------
// K0a: transpose + hi/lo split
// ---------------------------------------------------------------------------
__global__ void transpose_split(const float* __restrict__ in,
                                short* __restrict__ outh, short* __restrict__ outl,
                                int R, int C){
  int idx = blockIdx.x * 256 + threadIdx.x;
  if (idx < R * C){
    int r = idx / C, c = idx % C;
    short h, l; split2(in[(size_t)r * C + c], h, l);
    outh[(size_t)c * R + r] = h;
    outl[(size_t)c * R + r] = l;
  }
}

// K0b: plain transpose to single bf16 (for Wout)
__global__ void transpose_to_bf16(const float* __restrict__ in, short* __restrict__ out,
                                  int R, int C){
  int idx = blockIdx.x * 256 + threadIdx.x;
  if (idx < R * C){
    int r = idx / C, c = idx % C;
    out[(size_t)c * R + r] = f2bf(in[(size_t)r * C + c]);
  }
}

// ---------------------------------------------------------------------------
// K1: x [B=256][D=256][T=256] f32 -> xT_hi/xT_lo [(t*256+b)][d] bf16
// ---------------------------------------------------------------------------
__global__ __launch_bounds__(256) void transpose_x_split(const float* __restrict__ x,
                                                         short* __restrict__ xTh,
                                                         short* __restrict__ xTl){
  __shared__ float tile[64][65];
  const int b = blockIdx.x, d0 = blockIdx.y * 64, t0 = blockIdx.z * 64;
  const int tid = threadIdx.x;
  const float* xp = x + ((size_t)b * 256 + d0) * 256 + t0;
  for (int v = tid; v < 1024; v += 256){
    int r = v >> 4, c4 = (v & 15) * 4;
    float4 f = *(const float4*)(xp + (size_t)r * 256 + c4);
    tile[r][c4+0] = f.x; tile[r][c4+1] = f.y; tile[r][c4+2] = f.z; tile[r][c4+3] = f.w;
  }
  __syncthreads();
  for (int v = tid; v < 512; v += 256){
    int j = v >> 3, i8 = (v & 7) * 8;
    short8 oh, ol;
    #pragma unroll
    for (int u = 0; u < 8; ++u){ short h, l; split2(tile[i8 + u][j], h, l); oh[u] = h; ol[u] = l; }
    size_t off = ((size_t)(t0 + j) * 256 + b) * 256 + d0 + i8;
    *(short8*)(xTh + off) = oh;
    *(short8*)(xTl + off) = ol;
  }
}

// ---------------------------------------------------------------------------
// K2: split-precision GEMM (3-product), 128x128 tile, 4 waves (2x2 of 64x64).
// ---------------------------------------------------------------------------
__global__ __launch_bounds__(256) void gemm1_split(
    const short* __restrict__ Ah, const short* __restrict__ Al,
    const short* __restrict__ Bh, const short* __restrict__ Bl,
    const float* __restrict__ bias, float* __restrict__ C0, float* __restrict__ C1,
    int M, int N, int K)
{
  __shared__ short lAh[128][72];
  __shared__ short lAl[128][72];
  __shared__ short lBh[128][72];
  __shared__ short lBl[128][72];
  const int m0 = blockIdx.y * 128, n0 = blockIdx.x * 128;
  const int tid = threadIdx.x;
  const int lane = tid & 63, wave = tid >> 6;
  const int wm = (wave >> 1) * 64, wn = (wave & 1) * 64;
  f32x4 acc[4][4] = {};
  for (int k0 = 0; k0 < K; k0 += 64){
    __syncthreads();
    for (int v = tid; v < 4096; v += 256){
      int sel = v >> 10, idx = v & 1023;
      int r = idx >> 3, c = (idx & 7) * 8;
      const short* src = (sel == 0) ? Ah + (size_t)(m0 + r) * K + k0 + c
                       : (sel == 1) ? Al + (size_t)(m0 + r) * K + k0 + c
                       : (sel == 2) ? Bh + (size_t)(n0 + r) * K + k0 + c
                                    : Bl + (size_t)(n0 + r) * K + k0 + c;
      short8 val = *(const short8*)src;
      short* dst = (sel == 0) ? &lAh[r][c] : (sel == 1) ? &lAl[r][c]
                 : (sel == 2) ? &lBh[r][c] : &lBl[r][c];
      *(short8*)dst = val;
    }
    __syncthreads();
    #pragma unroll
    for (int kk = 0; kk < 64; kk += 32){
      int ko = kk + (lane >> 4) * 8;
      short8 ah[4], al[4], bh[4], bl[4];
      #pragma unroll
      for (int i = 0; i < 4; ++i){
        ah[i] = *(const short8*)&lAh[wm + i * 16 + (lane & 15)][ko];
        al[i] = *(const short8*)&lAl[wm + i * 16 + (lane & 15)][ko];
        bh[i] = *(const short8*)&lBh[wn + i * 16 + (lane & 15)][ko];
        bl[i] = *(const short8*)&lBl[wn + i * 16 + (lane & 15)][ko];
      }
      #pragma unroll
      for (int i = 0; i < 4; ++i)
      #pragma unroll
      for (int j = 0; j < 4; ++j){
        acc[i][j] = __builtin_amdgcn_mfma_f32_16x16x32_bf16(ah[i], bh[j], acc[i][j], 0, 0, 0);
        acc[i][j] = __builtin_amdgcn_mfma_f32_16x16x32_bf16(ah[i], bl[j], acc[i][j], 0, 0, 0);
        acc[i][j] = __builtin_amdgcn_mfma_f32_16x16x32_bf16(al[i], bh[j], acc[i][j], 0, 0, 0);
      }
    }
  }
  const int cr = (lane >> 4) * 4, cc = lane & 15;
  #pragma unroll
  for (int i = 0; i < 4; ++i)
  #pragma unroll
  for (int j = 0; j < 4; ++j){
    int row = m0 + wm + i * 16 + cr;
    int col = n0 + wn + j * 16 + cc;
    float bv = bias[col];
    float* base = (row < 32768) ? C0 : C1;
    int rr = (row < 32768) ? row : row - 32768;
    #pragma unroll
    for (int r = 0; r < 4; ++r){
      base[(size_t)(rr + r) * N + col] = acc[i][j][r] + bv;
    }
  }
}

// ---------------------------------------------------------------------------
// K3 v9: v5's proven protocol (256 blocks = 32 teams x 8 slices, 8 block-leader
// flags, s_sleep poll) + flag-preload overlapped with the publish drain
// (round-0 detect is free when producers already posted; own slice masked),
// xproj off the detect path (vmcnt(2) split), conflict-free LDS writes,
// 2 barriers/step.
// ---------------------------------------------------------------------------
__global__ __launch_bounds__(256, 1) void rnn_steps_v9(
    const float* __restrict__ xp0,    // t<128:  [(t*256+b)][512] f32
    const float* __restrict__ xp1,    // t>=128: [((t-128)*256+b)][512] f32
    const short* __restrict__ WhTh,   // [512][512] bf16 hi, [n][k]
    const short* __restrict__ WhTl,   // [512][512] bf16 lo
    const float* __restrict__ init,   // [512]
    short* __restrict__ states,       // [(b*256+t)][512] bf16
    unsigned* __restrict__ pay,       // [2][32][8][512] u32 payload
    unsigned* __restrict__ flags)     // [2][32][32] u32 (8 used/team)
{
  __shared__ short hh[16 * 512];      // h hi plane, swizzled, rows 8..15 zero
  __shared__ short hl[16 * 512];      // h lo plane
  const int tid = threadIdx.x, lane = tid & 63, wave = tid >> 6;
  const int team = blockIdx.x & 31, slice = blockIdx.x >> 5;
  const int b0 = team * 8;
  const int nc = slice * 64 + wave * 16;          // this wave's global col base

  // ---- prologue: Wh B-fragments into registers (hi+lo, 16 k-steps) ----
  short8 Bh[16], Bl[16];
  {
    const size_t col = (size_t)(nc + (lane & 15));
    const int kb0 = (lane >> 4) * 8;
    #pragma unroll
    for (int ks = 0; ks < 16; ++ks){
      Bh[ks] = *(const short8*)(WhTh + col * 512 + ks * 32 + kb0);
      Bl[ks] = *(const short8*)(WhTl + col * 512 + ks * 32 + kb0);
    }
    #pragma unroll
    for (int ks = 0; ks < 16; ++ks){
      asm volatile("" : "+v"(Bh[ks]), "+v"(Bl[ks]));
    }
  }
  // zero pad rows 8..15 once; fill rows 0..7 with init
  for (int v = tid; v < 8 * 512; v += 256){
    int r = 8 + (v >> 9), k = v & 511;
    hh[HIDX(r, k)] = 0; hl[HIDX(r, k)] = 0;
  }
  for (int v = tid; v < 8 * 512; v += 256){
    int r = v >> 9, k = v & 511;
    short hi, lo; split2(init[k], hi, lo);
    hh[HIDX(r, k)] = hi; hl[HIDX(r, k)] = lo;
  }
  __syncthreads();

  // ---- per-lane constants (same verified mapping as r2..r8) ----
  const int cc = lane & 15;
  const bool islo = (lane < 32);
  const int mbase = ((lane & 31) >> 4) * 4;
  const int m_0 = mbase + (islo ? 0 : 2);
  const int m_1 = mbase + (islo ? 1 : 3);
  const int n = nc + cc;                           // global col of this lane
  float hr0 = init[n], hr1 = init[n];              // fp32 residual masters

  const int am = lane & 15, kb = (lane >> 4) * 8;
  // conflict-free exchange-read/LDS-write assignment
  const int rr = tid & 7, c0 = ((tid >> 3) & 31) * 16;

  u32x4 pf0 = {}, pf1 = {};                        // preloaded flag line

  for (int t = 0; t < 256; ++t){
    float xv0, xv1;
    if (t == 0){
      xv0 = xp0[(size_t)(b0 + m_0) * 512 + n];
      xv1 = xp0[(size_t)(b0 + m_1) * 512 + n];
    } else {
      const unsigned tagv = (unsigned)t;
      // round 0: preloaded flags (own slice masked — own payload safe by
      // program order + drain). Retry loop = v5's proven poll.
      bool ok = (pf0.x >= tagv || slice == 0) && (pf0.y >= tagv || slice == 1) &&
                (pf0.z >= tagv || slice == 2) && (pf0.w >= tagv || slice == 3) &&
                (pf1.x >= tagv || slice == 4) && (pf1.y >= tagv || slice == 5) &&
                (pf1.z >= tagv || slice == 6) && (pf1.w >= tagv || slice == 7);
      if (!ok){
        const unsigned* flg = flags + (((size_t)(t & 1)) * 32 + team) * 32;
        while (true){
          __builtin_amdgcn_s_sleep(1);
          u32x4 f0, f1;
          asm volatile("global_load_dwordx4 %0, %1, off sc0 sc1" : "=&v"(f0) : "v"(flg)     : "memory");
          asm volatile("global_load_dwordx4 %0, %1, off sc0 sc1" : "=&v"(f1) : "v"(flg + 4) : "memory");
          asm volatile("s_waitcnt vmcnt(0)" : "+v"(f0), "+v"(f1) :: "memory");
          bool ok2 = (f0.x >= tagv || slice == 0) && (f0.y >= tagv || slice == 1) &&
                     (f0.z >= tagv || slice == 2) && (f0.w >= tagv || slice == 3) &&
                     (f1.x >= tagv || slice == 4) && (f1.y >= tagv || slice == 5) &&
                     (f1.z >= tagv || slice == 6) && (f1.w >= tagv || slice == 7);
          if (ok2) break;
        }
      }
      // issue payload (4x dwordx4) then xproj (2x dword); wait payload only.
      // No barrier needed here: the tail barrier of step t-1 already gated
      // all waves past their MFMA reads of the LDS planes.
      const unsigned* src = pay + ((((size_t)(t & 1)) * 32 + team) * 8 + rr) * 512 + c0;
      u32x4 g0, g1, g2, g3;
      asm volatile("global_load_dwordx4 %0, %1, off sc0 sc1" : "=&v"(g0) : "v"(src +  0) : "memory");
      asm volatile("global_load_dwordx4 %0, %1, off sc0 sc1" : "=&v"(g1) : "v"(src +  4) : "memory");
      asm volatile("global_load_dwordx4 %0, %1, off sc0 sc1" : "=&v"(g2) : "v"(src +  8) : "memory");
      asm volatile("global_load_dwordx4 %0, %1, off sc0 sc1" : "=&v"(g3) : "v"(src + 12) : "memory");
      const float* xpb = (t < 128) ? xp0 : xp1;
      const int tt = (t < 128) ? t : t - 128;
      const float* xa0 = xpb + ((size_t)tt * 256 + b0 + m_0) * 512 + n;
      const float* xa1 = xpb + ((size_t)tt * 256 + b0 + m_1) * 512 + n;
      asm volatile("global_load_dword %0, %1, off" : "=&v"(xv0) : "v"(xa0) : "memory");
      asm volatile("global_load_dword %0, %1, off" : "=&v"(xv1) : "v"(xa1) : "memory");
      // in-order vmcnt: waits the 4 payload loads, leaves the 2 xproj in flight
      asm volatile("s_waitcnt vmcnt(2)"
                   : "+v"(g0), "+v"(g1), "+v"(g2), "+v"(g3) :: "memory");
      short8 h0v, h1v, l0v, l1v;
      h0v[0] = (short)(g0.x >> 16); h0v[1] = (short)(g0.y >> 16);
      h0v[2] = (short)(g0.z >> 16); h0v[3] = (short)(g0.w >> 16);
      h0v[4] = (short)(g1.x >> 16); h0v[5] = (short)(g1.y >> 16);
      h0v[6] = (short)(g1.z >> 16); h0v[7] = (short)(g1.w >> 16);
      h1v[0] = (short)(g2.x >> 16); h1v[1] = (short)(g2.y >> 16);
      h1v[2] = (short)(g2.z >> 16); h1v[3] = (short)(g2.w >> 16);
      h1v[4] = (short)(g3.x >> 16); h1v[5] = (short)(g3.y >> 16);
      h1v[6] = (short)(g3.z >> 16); h1v[7] = (short)(g3.w >> 16);
      l0v[0] = (short)(g0.x & 0xffffu); l0v[1] = (short)(g0.y & 0xffffu);
      l0v[2] = (short)(g0.z & 0xffffu); l0v[3] = (short)(g0.w & 0xffffu);
      l0v[4] = (short)(g1.x & 0xffffu); l0v[5] = (short)(g1.y & 0xffffu);
      l0v[6] = (short)(g1.z & 0xffffu); l0v[7] = (short)(g1.w & 0xffffu);
      l1v[0] = (short)(g2.x & 0xffffu); l1v[1] = (short)(g2.y & 0xffffu);
      l1v[2] = (short)(g2.z & 0xffffu); l1v[3] = (short)(g2.w & 0xffffu);
      l1v[4] = (short)(g3.x & 0xffffu); l1v[5] = (short)(g3.y & 0xffffu);
      l1v[6] = (short)(g3.z & 0xffffu); l1v[7] = (short)(g3.w & 0xffffu);
      *(short8*)&hh[HIDX(rr, c0)]     = h0v;
      *(short8*)&hh[HIDX(rr, c0 + 8)] = h1v;
      *(short8*)&hl[HIDX(rr, c0)]     = l0v;
      *(short8*)&hl[HIDX(rr, c0 + 8)] = l1v;
      __syncthreads();   // h_t complete in LDS
    }

    // MFMA: 3 independent accumulator chains (hh, hl, lh)
    f32x4 ahh = {}, ahl = {}, alh = {};
    #pragma unroll
    for (int ks = 0; ks < 16; ++ks){
      short8 Ah = *(const short8*)&hh[HIDX(am, ks * 32 + kb)];
      short8 Al = *(const short8*)&hl[HIDX(am, ks * 32 + kb)];
      ahh = __builtin_amdgcn_mfma_f32_16x16x32_bf16(Ah, Bh[ks], ahh, 0, 0, 0);
      ahl = __builtin_amdgcn_mfma_f32_16x16x32_bf16(Ah, Bl[ks], ahl, 0, 0, 0);
      alh = __builtin_amdgcn_mfma_f32_16x16x32_bf16(Al, Bh[ks], alh, 0, 0, 0);
    }
    const float s0 = ahh[0] + (ahl[0] + alh[0]);
    const float s1 = ahh[1] + (ahl[1] + alh[1]);
    const float s2 = ahh[2] + (ahl[2] + alh[2]);
    const float s3 = ahh[3] + (ahl[3] + alh[3]);
    const float t2 = __shfl(s2, lane ^ 32);
    const float t3 = __shfl(s3, lane ^ 32);
    const float v0 = islo ? s0 : t2;
    const float v1 = islo ? s1 : t3;

    if (t > 0){
      asm volatile("s_waitcnt vmcnt(0)" : "+v"(xv0), "+v"(xv1) :: "memory");
    }
    const float hn0 = tanh_fast(xv0 + v0) + hr0;
    const float hn1 = tanh_fast(xv1 + v1) + hr1;
    hr0 = hn0; hr1 = hn1;

    if (t < 255){
      // publish payload + states, preload next flag line, one drain for all,
      // block barrier, leader posts flag.
      unsigned* dst = pay + ((((size_t)((t + 1) & 1)) * 32 + team) * 8) * 512;
      unsigned w0 = pack2(hn0), w1 = pack2(hn1);
      unsigned* a0 = dst + (size_t)m_0 * 512 + n;
      unsigned* a1 = dst + (size_t)m_1 * 512 + n;
      asm volatile("global_store_dword %0, %1, off sc0 sc1" :: "v"(a0), "v"(w0) : "memory");
      asm volatile("global_store_dword %0, %1, off sc0 sc1" :: "v"(a1), "v"(w1) : "memory");
      states[((size_t)(b0 + m_0) * 256 + t) * 512 + n] = f2bf(hn0);
      states[((size_t)(b0 + m_1) * 256 + t) * 512 + n] = f2bf(hn1);
      const unsigned* nflg = flags + (((size_t)((t + 1) & 1)) * 32 + team) * 32;
      asm volatile("global_load_dwordx4 %0, %1, off sc0 sc1" : "=&v"(pf0) : "v"(nflg)     : "memory");
      asm volatile("global_load_dwordx4 %0, %1, off sc0 sc1" : "=&v"(pf1) : "v"(nflg + 4) : "memory");
      asm volatile("s_waitcnt vmcnt(0)" : "+v"(pf0), "+v"(pf1) :: "memory");
      __syncthreads();
      if (tid == 0){
        unsigned* fdst = flags + (((size_t)((t + 1) & 1)) * 32 + team) * 32 + slice;
        unsigned tagn = (unsigned)(t + 1);
        asm volatile("global_store_dword %0, %1, off sc0 sc1" :: "v"(fdst), "v"(tagn) : "memory");
      }
    } else {
      states[((size_t)(b0 + m_0) * 256 + t) * 512 + n] = f2bf(hn0);
      states[((size_t)(b0 + m_1) * 256 + t) * 512 + n] = f2bf(hn1);
    }
  }
}

// ---------------------------------------------------------------------------
// K4: single-product bf16 GEMM, 128x128 tile, 4 waves (2x2 of 64x64), fp32 out.
// ---------------------------------------------------------------------------
__global__ __launch_bounds__(256) void gemm_bias_f32(
    const short* __restrict__ A, const short* __restrict__ Bt,
    const float* __restrict__ bias, float* __restrict__ C,
    int M, int N, int K)
{
  __shared__ short lA[128][72];
  __shared__ short lB[128][72];
  const int m0 = blockIdx.y * 128, n0 = blockIdx.x * 128;
  const int tid = threadIdx.x;
  const int lane = tid & 63, wave = tid >> 6;
  const int wm = (wave >> 1) * 64, wn = (wave & 1) * 64;
  f32x4 acc[4][4] = {};
  for (int k0 = 0; k0 < K; k0 += 64){
    __syncthreads();
    for (int v = tid; v < 2048; v += 256){
      int sel = v >> 10, idx = v & 1023;
      int r = idx >> 3, c = (idx & 7) * 8;
      const short* src = (sel == 0) ? A + (size_t)(m0 + r) * K + k0 + c
                                    : Bt + (size_t)(n0 + r) * K + k0 + c;
      short8 val = *(const short8*)src;
      short* dst = (sel == 0) ? &lA[r][c] : &lB[r][c];
      *(short8*)dst = val;
    }
    __syncthreads();
    #pragma unroll
    for (int kk = 0; kk < 64; kk += 32){
      int ko = kk + (lane >> 4) * 8;
      short8 a[4], b[4];
      #pragma unroll
      for (int i = 0; i < 4; ++i){
        a[i] = *(const short8*)&lA[wm + i * 16 + (lane & 15)][ko];
        b[i] = *(const short8*)&lB[wn + i * 16 + (lane & 15)][ko];
      }
      #pragma unroll
      for (int i = 0; i < 4; ++i)
      #pragma unroll
      for (int j = 0; j < 4; ++j){
        acc[i][j] = __builtin_amdgcn_mfma_f32_16x16x32_bf16(a[i], b[j], acc[i][j], 0, 0, 0);
      }
    }
  }
  const int cr = (lane >> 4) * 4, cc = lane & 15;
  #pragma unroll
  for (int i = 0; i < 4; ++i)
  #pragma unroll
  for (int j = 0; j < 4; ++j){
    int row = m0 + wm + i * 16 + cr;
    int col = n0 + wn + j * 16 + cc;
    float bv = bias[col];
    #pragma unroll
    for (int r = 0; r < 4; ++r){
      C[(size_t)(row + r) * N + col] = acc[i][j][r] + bv;
    }
  }
}

// ---------------------------------------------------------------------------
extern "C" void kernel_launch(void* const* d_in, const int* in_sizes, int n_in,
                              void* d_out, int out_size, void* d_ws, size_t ws_size,
                              hipStream_t stream){
  (void)in_sizes; (void)n_in; (void)out_size;
  const float* x    = (const float*)d_in[0];
  const float* Wx   = (const float*)d_in[1];
  const float* Wh   = (const float*)d_in[2];
  const float* bias = (const float*)d_in[3];
  const float* Wout = (const float*)d_in[4];
  const float* bout = (const float*)d_in[5];
  const float* init = (const float*)d_in[6];
  float* out = (float*)d_out;

  char* p = (char*)d_ws;
  // [0,64Mi): xT hi+lo during GEMM1, then states (written only by rnn).
  short* xTh    = (short*)(p);
  short* xTl    = (short*)(p + 33554432);
  short* states = (short*)(p);
  // xproj fp32: rows [0,32768) in ws, rows [32768,65536) in d_out (dead until GEMM2).
  float* xproj0 = (float*)(p + 67108864);     // 64 MiB
  float* xproj1 = (float*)d_out;              // 64 MiB
  short* WxTh   = (short*)(p + 134217728);    // 256 KiB
  short* WxTl   = (short*)(p + 134479872);    // 256 KiB
  short* WhTh   = (short*)(p + 134742016);    // 512 KiB
  short* WhTl   = (short*)(p + 135266304);    // 512 KiB
  short* WoutT  = (short*)(p + 135790592);    // 256 KiB
  unsigned* pay   = (unsigned*)(p + 136052736); // 1 MiB  [2][32][8][512] u32
  unsigned* flags = (unsigned*)(p + 137101312); // 8 KiB  [2][32][32] u32
  if (ws_size < 137109504u){
    fprintf(stderr, "kernel_launch: ws_size=%zu < 137109504 needed\n", ws_size);
  }

  // clear flags every launch (graph-capture-safe); payload gated by flags
  hipMemsetAsync(flags, 0, 8192, stream);

  transpose_split<<<(256*512 + 255)/256, 256, 0, stream>>>(Wx, WxTh, WxTl, 256, 512);
  transpose_split<<<(512*512 + 255)/256, 256, 0, stream>>>(Wh, WhTh, WhTl, 512, 512);
  transpose_to_bf16<<<(512*256 + 255)/256, 256, 0, stream>>>(Wout, WoutT, 512, 256);
  transpose_x_split<<<dim3(256, 4, 4), 256, 0, stream>>>(x, xTh, xTl);
  // xproj = xT @ Wx + b at ~fp32 precision (3-product split MFMA), 128^2 tile
  gemm1_split<<<dim3(4, 512), 256, 0, stream>>>(xTh, xTl, WxTh, WxTl, bias,
                                                xproj0, xproj1, 65536, 512, 256);
  // recurrence: 32 teams x 8 slices, v9 protocol
  rnn_steps_v9<<<256, 256, 0, stream>>>(xproj0, xproj1, WhTh, WhTl, init,
                                        states, pay, flags);
  // out = states @ Wout + bout (single bf16 product), 128^2 tile
  gemm_bias_f32<<<dim3(2, 512), 256, 0, stream>>>(states, WoutT, bout, out, 65536, 256, 512);
}